// Round 7
// baseline (335.844 us; speedup 1.0000x reference)
//
#include <hip/hip_runtime.h>
#include <hip/hip_bf16.h>

// CrossCovarianceAttn (XCiT channel attention), MI355X gfx950.
// Pipeline:
//   K0: transpose+cast Wqkv -> WqkvT bf16 [2304][768]
//   Kc: cast x fp32 -> xB bf16 (stored in d_out scratch, overwritten by K5)
//   K1: GEMM1 qkvB = bf16(xB @ Wqkv + bqkv)  (256x256, 1-barrier/K-tile)
//   K2: per (b,h,split): 128x128 Gram of [q|k] (dbuf LDS, early reg loads)
//   K3: reduce partials -> norms + softmax -> attn [48][64][64] fp32
//   K4: WcombT[b][j][h*64+e] = sum_d attn[b,h,d,e] * Wproj[h*64+d][j]  (bf16)
//   K5: GEMM2 out = V @ Wcomb[b] + bproj  (fp32 out, same template)

using short8 = __attribute__((ext_vector_type(8))) short;
using f32x4  = __attribute__((ext_vector_type(4))) float;

#define B_   4
#define N_   8192
#define C_   768
#define H_   12
#define HD_  64
#define N1_  (3*C_)      // 2304
#define MTOT (B_*N_)     // 32768
#define SPLITS 8
#define NCHUNK (N_/SPLITS)  // 1024

__device__ __forceinline__ unsigned short f2b(float f){
  union { float f; unsigned u; } v; v.f = f;
  unsigned u = v.u;
  u += 0x7fffu + ((u >> 16) & 1u);   // RNE
  return (unsigned short)(u >> 16);
}

// async global->LDS, 16B per lane; LDS dest = wave-uniform base + lane*16
#define GLOAD_LDS16(g, l) \
  __builtin_amdgcn_global_load_lds((const __attribute__((address_space(1))) void*)(g), \
                                   (__attribute__((address_space(3))) void*)(l), 16, 0, 0)

// ---------------- K0: Wqkv [768][2304] fp32 -> WqkvT [2304][768] bf16 ----
__global__ __launch_bounds__(256)
void transpose_w(const float* __restrict__ W, unsigned short* __restrict__ Wt,
                 int rows, int cols)
{
  __shared__ float tile[32][33];
  const int ctiles = cols / 32;
  const int bx = blockIdx.x % ctiles;
  const int by = blockIdx.x / ctiles;
  const int t = threadIdx.x;
  const int c = t & 31;
  #pragma unroll
  for (int i = 0; i < 4; ++i){
    int r = i*8 + (t >> 5);
    tile[r][c] = W[(long)(by*32 + r)*cols + bx*32 + c];
  }
  __syncthreads();
  #pragma unroll
  for (int i = 0; i < 4; ++i){
    int r = i*8 + (t >> 5);
    Wt[(long)(bx*32 + r)*rows + by*32 + c] = f2b(tile[c][r]);
  }
}

// ---------------- Kc: x fp32 -> bf16, 8 elems/thread, grid-stride ---------
__global__ __launch_bounds__(256)
void cvt_bf16(const float* __restrict__ in, unsigned short* __restrict__ out, long n8)
{
  long idx = (long)blockIdx.x*256 + threadIdx.x;
  const long stride = (long)gridDim.x*256;
  for (; idx < n8; idx += stride){
    const long i = idx*8;
    f32x4 v0 = *(const f32x4*)(in + i);
    f32x4 v1 = *(const f32x4*)(in + i + 4);
    uint4 o;
    o.x = (unsigned)f2b(v0[0]) | ((unsigned)f2b(v0[1]) << 16);
    o.y = (unsigned)f2b(v0[2]) | ((unsigned)f2b(v0[3]) << 16);
    o.z = (unsigned)f2b(v1[0]) | ((unsigned)f2b(v1[1]) << 16);
    o.w = (unsigned)f2b(v1[2]) | ((unsigned)f2b(v1[3]) << 16);
    *(uint4*)(out + i) = o;
  }
}

// ================= 256x256 GEMM, 1 barrier per K-tile ======================
// A [M rows][LDA] bf16 (+a_off elems), B pre-transposed [N rows][K_] bf16.
// 512 threads = 8 waves as 2M x 4N: per-wave C = 128 rows x 64 cols.
// Round-7 schedule: within a K-tile the read buffer RB is stable and stages
// go to RB^1, so intra-tile barriers are unnecessary. Per tile:
//   vmcnt(0) + s_barrier              (stages for kt landed, all waves here)
//   issue 8 gload_lds (tile kt+1 -> RB^1)
//   issue 20 ds_read_b128 (afL, bfr01, afH)
//   Q00, Q10                          (compiler emits counted lgkmcnt)
//   issue 4 ds_read (bfr23 -> bfr regs, WAR-ordered after Q10)
//   Q01, Q11
// LDS drain (2304 cyc) overlaps MFMA issue (2483 cyc) within and across
// waves; waves drift within a tile and re-sync at the boundary barrier.
// Safety: a wave's RB^1 reads (tile kt-1) complete before its Q01 MFMAs
// issue (in-order DS completion), which precedes its arrival at tile kt's
// barrier -> post-barrier stages into RB^1 cannot race any reader.
// T2 both-sides swizzle: 16B slot ^= (row&7) at the GLOBAL source and on
// ds_read (rule #21).  NT-inner block order: A-panel L2 reuse (round 6).
template<int OUT_B16, int B_PER_B, int LDA, int K_>
__global__ __launch_bounds__(512, 2)
void gemm256(const unsigned short* __restrict__ A, int a_off,
             const unsigned short* __restrict__ Bt,
             const float* __restrict__ bias,
             void* __restrict__ Outp, int ldo, int Ntiles)
{
  __shared__ unsigned short As[2][256][64];   // 64 KiB
  __shared__ unsigned short Bs[2][256][64];   // 64 KiB
  const int t = threadIdx.x;
  const int lane = t & 63, w = t >> 6;
  const int wm = w >> 2, wn = w & 3;          // 2M x 4N wave grid
  // XCD-aware bijective swizzle (gridDim.x % 8 == 0 for all launches here)
  const int nwg = gridDim.x, cpx = nwg >> 3;
  const int bid = (int)blockIdx.x;
  const int swz = (bid & 7) * cpx + (bid >> 3);
  const int mt = swz / Ntiles, nt = swz % Ntiles;   // nt-inner: A-panel reuse
  const long m0 = (long)mt * 256;
  const int  n0 = nt * 256;
  const unsigned short* B0p = Bt + (B_PER_B ? (long)(m0 / N_) * C_ * C_ : 0);
  // staging lane geometry: lane covers (row rowin of an 8-row group, slot L&7)
  const int rowin = lane >> 3;
  const int swzc  = ((lane & 7) ^ rowin) * 8;         // pre-swizzled global col
  const unsigned short* Ag = A + a_off + (m0 + rowin) * (long)LDA + swzc;
  const unsigned short* Bg = B0p + (long)(n0 + rowin) * (long)K_ + swzc;
  const int KT = K_ / 64;                              // 12 (even)

#define STG_A(wb, half, k0g) do{ _Pragma("unroll")                         \
  for (int j_ = 0; j_ < 2; ++j_){                                          \
    const int rg_ = (half)*128 + (w*2 + j_)*8;                             \
    GLOAD_LDS16(Ag + (long)rg_*LDA + (k0g), &As[wb][rg_][0]); } }while(0)
#define STG_B(wb, half, k0g) do{ _Pragma("unroll")                         \
  for (int j_ = 0; j_ < 2; ++j_){                                          \
    const int rg_ = (half)*128 + (w*2 + j_)*8;                             \
    GLOAD_LDS16(Bg + (long)rg_*K_ + (k0g), &Bs[wb][rg_][0]); } }while(0)

  const int l15 = lane & 15, l4 = lane >> 4, x7 = l15 & 7;
  const int ca = (l4 ^ x7) * 8;        // kh=0 swizzled elem col
  const int cb = ((4 + l4) ^ x7) * 8;  // kh=1 swizzled elem col

  f32x4 acc[8][4] = {};
  short8 afL[4][2], afH[4][2], bfr[2][2];

#define RD_A(dst, RB, mbase) do{ _Pragma("unroll")                         \
  for (int i_ = 0; i_ < 4; ++i_){                                          \
    const int row_ = wm*128 + ((mbase) + i_)*16 + l15;                     \
    dst[i_][0] = *(const short8*)&As[RB][row_][ca];                        \
    dst[i_][1] = *(const short8*)&As[RB][row_][cb]; } }while(0)
#define RD_B(dst, RB, nbase) do{ _Pragma("unroll")                         \
  for (int i_ = 0; i_ < 2; ++i_){                                          \
    const int row_ = wn*64 + ((nbase) + i_)*16 + l15;                      \
    dst[i_][0] = *(const short8*)&Bs[RB][row_][ca];                        \
    dst[i_][1] = *(const short8*)&Bs[RB][row_][cb]; } }while(0)

#define MFMA_Q(afr, bfq, mo, no) do{                                       \
    __builtin_amdgcn_s_setprio(1);                                         \
    _Pragma("unroll")                                                      \
    for (int i_ = 0; i_ < 4; ++i_)                                         \
      _Pragma("unroll")                                                    \
      for (int j_ = 0; j_ < 2; ++j_){                                      \
        acc[(mo)+i_][(no)+j_] = __builtin_amdgcn_mfma_f32_16x16x32_bf16(   \
            afr[i_][0], bfq[j_][0], acc[(mo)+i_][(no)+j_], 0, 0, 0);       \
        acc[(mo)+i_][(no)+j_] = __builtin_amdgcn_mfma_f32_16x16x32_bf16(   \
            afr[i_][1], bfq[j_][1], acc[(mo)+i_][(no)+j_], 0, 0, 0);       \
      }                                                                    \
    __builtin_amdgcn_s_setprio(0);                                         \
  }while(0)

#define BARRIER()  asm volatile("s_barrier" ::: "memory")
#define WAITVM0()  asm volatile("s_waitcnt vmcnt(0)" ::: "memory")
#define SB0()      __builtin_amdgcn_sched_barrier(0)

// One K-tile, buffer index RB is a literal. Stages tile kt+1 into RB^1.
#define TILE(RB, kt_, ST_) do{                                             \
    const int k1_ = ((kt_) + 1) * 64;                                      \
    WAITVM0();                        /* tile kt's stage loads landed */   \
    BARRIER();                        /* all waves: RB^1 fully read    */  \
    if (ST_){ STG_B((RB)^1, 0, k1_); STG_B((RB)^1, 1, k1_);                \
              STG_A((RB)^1, 0, k1_); STG_A((RB)^1, 1, k1_); }              \
    SB0();                                                                 \
    RD_A(afL, RB, 0);                                                      \
    RD_B(bfr, RB, 0);                                                      \
    RD_A(afH, RB, 4);                                                      \
    SB0();                            /* reads issued before MFMA region */\
    MFMA_Q(afL, bfr, 0, 0);                                                \
    MFMA_Q(afH, bfr, 4, 0);                                                \
    SB0();                                                                 \
    RD_B(bfr, RB, 2);                 /* WAR: ordered after Q10 */         \
    SB0();                                                                 \
    MFMA_Q(afL, bfr, 0, 2);                                                \
    MFMA_Q(afH, bfr, 4, 2);                                                \
  }while(0)

  // prologue: stage tile 0 into buf 0
  STG_B(0, 0, 0); STG_B(0, 1, 0); STG_A(0, 0, 0); STG_A(0, 1, 0);

  #pragma unroll 1
  for (int it = 0; it < KT/2; ++it){
    const int kt0 = it*2;
    TILE(0, kt0, true);                      // kt0 <= KT-2: always stages
    TILE(1, kt0 + 1, (kt0 + 1) < (KT - 1));  // last tile stages nothing
  }

#undef TILE
#undef SB0
#undef WAITVM0
#undef BARRIER
#undef MFMA_Q
#undef RD_B
#undef RD_A
#undef STG_B
#undef STG_A

  // epilogue: C write (C/D layout: col=lane&15, row=(lane>>4)*4+j)
  const int rl = l4 * 4, cl = l15;
  #pragma unroll
  for (int mi = 0; mi < 8; ++mi){
    const long gr = m0 + wm*128 + mi*16 + rl;
    #pragma unroll
    for (int ni = 0; ni < 4; ++ni){
      const int gc = n0 + wn*64 + ni*16 + cl;
      const float bv = bias[gc];
      #pragma unroll
      for (int j = 0; j < 4; ++j){
        float v = acc[mi][ni][j] + bv;
        if (OUT_B16) ((unsigned short*)Outp)[(gr + j)*(long)ldo + gc] = f2b(v);
        else         ((float*)Outp)[(gr + j)*(long)ldo + gc] = v;
      }
    }
  }
}

// ---------------- K2: per (b,h,split) 128x128 Gram of stacked [q|k] ------
__global__ __launch_bounds__(256)
void gram_qk(const unsigned short* __restrict__ qkv, float* __restrict__ part)
{
  __shared__ unsigned short Xs[2][128][72];   // padded: conflict-light ds_read
  const int sp = blockIdx.x;               // 0..SPLITS-1
  const int bh = blockIdx.y;               // 0..47
  const int b = bh / H_, h = bh % H_;
  const int t = threadIdx.x, lane = t & 63, w = t >> 6, wr = w >> 1, wc = w & 1;
  f32x4 acc[4][4] = {};
  const long rowbase = (long)b * N_ + (long)sp * NCHUNK;
  const int c8  = t & 15;                  // channel-octet this thread stages
  const int col = (c8 < 8) ? (h*HD_ + c8*8) : (C_ + h*HD_ + (c8 - 8)*8);
  const int nl0 = t >> 4;                  // base n-row (i adds 16)
  uint4 r[4];

  #pragma unroll
  for (int i = 0; i < 4; ++i)
    r[i] = *(const uint4*)(qkv + (rowbase + i*16 + nl0)*N1_ + col);

  int cur = 0;
  for (int st = 0; st < NCHUNK/64; ++st){
    #pragma unroll
    for (int i = 0; i < 4; ++i){
      const unsigned short* pv = (const unsigned short*)&r[i];
      #pragma unroll
      for (int j = 0; j < 8; ++j) Xs[cur][c8*8 + j][i*16 + nl0] = pv[j];
    }
    if (st + 1 < NCHUNK/64){
      #pragma unroll
      for (int i = 0; i < 4; ++i)
        r[i] = *(const uint4*)(qkv + (rowbase + (st+1)*64 + i*16 + nl0)*N1_ + col);
    }
    asm volatile("s_waitcnt lgkmcnt(0)" ::: "memory");  // ds_writes visible
    __builtin_amdgcn_s_barrier();                        // vmcnt stays in flight
    asm volatile("" ::: "memory");
    #pragma unroll
    for (int kk = 0; kk < 2; ++kk){
      const int koff = kk*32 + (lane >> 4) * 8;
      short8 a[4], bb[4];
      #pragma unroll
      for (int m = 0; m < 4; ++m)
        a[m] = *(const short8*)&Xs[cur][wr*64 + m*16 + (lane & 15)][koff];
      #pragma unroll
      for (int n = 0; n < 4; ++n)
        bb[n] = *(const short8*)&Xs[cur][wc*64 + n*16 + (lane & 15)][koff];
      #pragma unroll
      for (int m = 0; m < 4; ++m)
        #pragma unroll
        for (int n = 0; n < 4; ++n)
          acc[m][n] = __builtin_amdgcn_mfma_f32_16x16x32_bf16(a[m], bb[n], acc[m][n], 0, 0, 0);
    }
    cur ^= 1;
  }
  float* P = part + ((long)bh*SPLITS + sp) * 128 * 128;
  const int rl = (lane >> 4) * 4, cl = lane & 15;
  #pragma unroll
  for (int m = 0; m < 4; ++m)
    #pragma unroll
    for (int n = 0; n < 4; ++n)
      #pragma unroll
      for (int j = 0; j < 4; ++j)
        P[(wr*64 + m*16 + rl + j)*128 + wc*64 + n*16 + cl] = acc[m][n][j];
}

// ---------------- K3: reduce partials, norms, softmax -> attn ------------
// Vectorized: f32x4 loads over e, softmax fully in-register (no sl LDS).
__global__ __launch_bounds__(64)
void softmax_attn(const float* __restrict__ part, const float* __restrict__ temperature,
                  float* __restrict__ attn)
{
  const int bh = blockIdx.x, h = bh % H_;
  const int d = threadIdx.x;
  __shared__ float rnk[64];
  const float* P = part + (long)bh * SPLITS * 16384;
  float nq2 = 0.f, nk2 = 0.f;
  for (int s = 0; s < SPLITS; ++s){
    nq2 += P[s*16384 + d*128 + d];
    nk2 += P[s*16384 + (64 + d)*128 + 64 + d];
  }
  const float rq = 1.0f / fmaxf(sqrtf(nq2), 1e-12f);
  rnk[d] = 1.0f / fmaxf(sqrtf(nk2), 1e-12f);
  __syncthreads();
  f32x4 se[16] = {};
  for (int sp = 0; sp < SPLITS; ++sp){
    const float* row = P + sp*16384 + d*128 + 64;
    #pragma unroll
    for (int i = 0; i < 16; ++i) se[i] += *(const f32x4*)(row + i*4);
  }
  const float th = temperature[h];
  float mx = -1e30f;
  #pragma unroll
  for (int i = 0; i < 16; ++i)
    #pragma unroll
    for (int j = 0; j < 4; ++j){
      float v = th * se[i][j] * rq * rnk[i*4 + j];
      se[i][j] = v;
      mx = fmaxf(mx, v);
    }
  float sum = 0.f;
  #pragma unroll
  for (int i = 0; i < 16; ++i)
    #pragma unroll
    for (int j = 0; j < 4; ++j){
      float ex = expf(se[i][j] - mx);
      se[i][j] = ex;
      sum += ex;
    }
  const float rs = 1.0f / sum;
  float* dst = attn + (long)bh*4096 + d*64;
  #pragma unroll
  for (int i = 0; i < 16; ++i){
    f32x4 o = se[i] * rs;
    *(f32x4*)(dst + i*4) = o;
  }
}

// ---------------- K4: WcombT[b][j][h*64+e] = sum_d attn[d][e]*Wproj[h*64+d][j]
__global__ __launch_bounds__(256)
void wcomb(const float* __restrict__ attn, const float* __restrict__ Wproj,
           unsigned short* __restrict__ WcT)
{
  const int bh = blockIdx.x;            // 0..47
  const int jt = blockIdx.y;            // 0..5
  const int b = bh / H_, h = bh % H_;
  __shared__ float sa[64][64];
  const int t = threadIdx.x;
  #pragma unroll
  for (int i = 0; i < 16; ++i){
    int idx = i*256 + t;
    sa[idx >> 6][idx & 63] = attn[(long)bh*4096 + idx];
  }
  __syncthreads();
  const int j  = jt*128 + (t & 127);
  const int e0 = (t >> 7) * 32;
  float acc[32] = {};
  for (int d = 0; d < 64; ++d){
    float wp = Wproj[(long)(h*HD_ + d)*C_ + j];
    #pragma unroll
    for (int i = 0; i < 32; ++i) acc[i] += sa[d][e0 + i] * wp;
  }
  #pragma unroll
  for (int i = 0; i < 32; ++i)
    WcT[((long)b*C_ + j)*C_ + h*HD_ + e0 + i] = f2b(acc[i]);
}

// ---------------- launch --------------------------------------------------
extern "C" void kernel_launch(void* const* d_in, const int* in_sizes, int n_in,
                              void* d_out, int out_size, void* d_ws, size_t ws_size,
                              hipStream_t stream)
{
  const float* x      = (const float*)d_in[0];
  const float* Wqkv   = (const float*)d_in[1];
  const float* bqkv   = (const float*)d_in[2];
  const float* temper = (const float*)d_in[3];
  const float* Wproj  = (const float*)d_in[4];
  const float* bproj  = (const float*)d_in[5];
  float* out = (float*)d_out;

  char* wp = (char*)d_ws;
  unsigned short* qkvB  = (unsigned short*)wp; wp += (size_t)MTOT * N1_ * 2;      // 151.0 MB
  unsigned short* WqkvT = (unsigned short*)wp; wp += (size_t)N1_ * C_ * 2;        // 3.5 MB
  unsigned short* WcT   = (unsigned short*)wp; wp += (size_t)B_ * C_ * C_ * 2;    // 4.7 MB
  float* part           = (float*)wp;          wp += (size_t)48 * SPLITS * 128 * 128 * 4; // 25.2 MB
  float* attn           = (float*)wp;          wp += (size_t)48 * 64 * 64 * 4;    // 0.79 MB
  // xB (48 MB) lives in d_out (96 MB fp32): consumed by K1, then K5 fully
  // overwrites d_out. Deterministic: same sequence every call.
  unsigned short* xB = (unsigned short*)d_out;

  // K0: WqkvT
  transpose_w<<<(N1_/32) * (C_/32), 256, 0, stream>>>(Wqkv, WqkvT, C_, N1_);
  // Kc: xB = bf16(x)
  cvt_bf16<<<2048, 256, 0, stream>>>(x, xB, (long)MTOT * C_ / 8);
  // K1: qkvB = bf16(xB @ Wqkv + bqkv); grid 128 x 9 = 1152 (%8==0), nt-inner
  gemm256<1,0,C_,C_><<<(MTOT/256) * (N1_/256), 512, 0, stream>>>(
      xB, 0, WqkvT, bqkv, (void*)qkvB, N1_, N1_/256);
  // K2: Gram partials
  gram_qk<<<dim3(SPLITS, 48), 256, 0, stream>>>(qkvB, part);
  // K3: softmax
  softmax_attn<<<48, 64, 0, stream>>>(part, temper, attn);
  // K4: combined weights
  wcomb<<<dim3(48, 6), 256, 0, stream>>>(attn, Wproj, WcT);
  // K5: out = V @ Wcomb[b] + bproj; grid 128 x 3 = 384 (%8==0), nt-inner
  gemm256<0,1,N1_,C_><<<(MTOT/256) * (C_/256), 512, 0, stream>>>(
      qkvB, 2*C_, WcT, bproj, (void*)out, C_, C_/256);
}

// Round 8
// 329.084 us; speedup vs baseline: 1.0205x; 1.0205x over previous
//
#include <hip/hip_runtime.h>
#include <hip/hip_bf16.h>

// CrossCovarianceAttn (XCiT channel attention), MI355X gfx950.
// Pipeline:
//   K0: transpose+cast Wqkv -> WqkvT bf16 [2304][768]
//   Kc: cast x fp32 -> xB bf16 (stored in d_out scratch, overwritten by K5)
//   K1: GEMM1 qkvB = bf16(xB @ Wqkv + bqkv)  (128x128, dbuf, 2 blocks/CU)
//   K2: per (b,h,split): 128x128 Gram of [q|k] (dbuf LDS, early reg loads)
//   K3: reduce partials -> norms + softmax -> attn [48][64][64] fp32
//   K4: WcombT[b][j][h*64+e] = sum_d attn[b,h,d,e] * Wproj[h*64+d][j]  (bf16)
//   K5: GEMM2 out = V @ Wcomb[b] + bproj  (fp32 out, same template)

using short8 = __attribute__((ext_vector_type(8))) short;
using f32x4  = __attribute__((ext_vector_type(4))) float;

#define B_   4
#define N_   8192
#define C_   768
#define H_   12
#define HD_  64
#define N1_  (3*C_)      // 2304
#define MTOT (B_*N_)     // 32768
#define SPLITS 8
#define NCHUNK (N_/SPLITS)  // 1024

__device__ __forceinline__ unsigned short f2b(float f){
  union { float f; unsigned u; } v; v.f = f;
  unsigned u = v.u;
  u += 0x7fffu + ((u >> 16) & 1u);   // RNE
  return (unsigned short)(u >> 16);
}

// async global->LDS, 16B per lane; LDS dest = wave-uniform base + lane*16
#define GLOAD_LDS16(g, l) \
  __builtin_amdgcn_global_load_lds((const __attribute__((address_space(1))) void*)(g), \
                                   (__attribute__((address_space(3))) void*)(l), 16, 0, 0)

// ---------------- K0: Wqkv [768][2304] fp32 -> WqkvT [2304][768] bf16 ----
__global__ __launch_bounds__(256)
void transpose_w(const float* __restrict__ W, unsigned short* __restrict__ Wt,
                 int rows, int cols)
{
  __shared__ float tile[32][33];
  const int ctiles = cols / 32;
  const int bx = blockIdx.x % ctiles;
  const int by = blockIdx.x / ctiles;
  const int t = threadIdx.x;
  const int c = t & 31;
  #pragma unroll
  for (int i = 0; i < 4; ++i){
    int r = i*8 + (t >> 5);
    tile[r][c] = W[(long)(by*32 + r)*cols + bx*32 + c];
  }
  __syncthreads();
  #pragma unroll
  for (int i = 0; i < 4; ++i){
    int r = i*8 + (t >> 5);
    Wt[(long)(bx*32 + r)*rows + by*32 + c] = f2b(tile[c][r]);
  }
}

// ---------------- Kc: x fp32 -> bf16, 8 elems/thread, grid-stride ---------
__global__ __launch_bounds__(256)
void cvt_bf16(const float* __restrict__ in, unsigned short* __restrict__ out, long n8)
{
  long idx = (long)blockIdx.x*256 + threadIdx.x;
  const long stride = (long)gridDim.x*256;
  for (; idx < n8; idx += stride){
    const long i = idx*8;
    f32x4 v0 = *(const f32x4*)(in + i);
    f32x4 v1 = *(const f32x4*)(in + i + 4);
    uint4 o;
    o.x = (unsigned)f2b(v0[0]) | ((unsigned)f2b(v0[1]) << 16);
    o.y = (unsigned)f2b(v0[2]) | ((unsigned)f2b(v0[3]) << 16);
    o.z = (unsigned)f2b(v1[0]) | ((unsigned)f2b(v1[1]) << 16);
    o.w = (unsigned)f2b(v1[2]) | ((unsigned)f2b(v1[3]) << 16);
    *(uint4*)(out + i) = o;
  }
}

// ================= 128x128 GEMM, dbuf, 2 blocks/CU =========================
// A [M rows][LDA] bf16 (+a_off elems), B pre-transposed [N rows][K_] bf16.
// 256 threads = 4 waves as 2M x 2N: per-wave C = 64x64, acc[4][4] f32x4.
// LDS: 2buf x (A 128x64 + B 128x64) bf16 = 64 KiB -> 2 blocks/CU.
// Round-8 rationale: rounds 5-7 showed a single 8-wave barrier group
// serializes LDS-phase and MFMA-phase (pipes take turns, MfmaUtil 30%).
// Two desynchronized blocks per CU overlap them (m114 mechanism): when
// block A drains ds_reads, block B issues MFMA.
// Per K-tile (1 barrier): vmcnt(0)+s_barrier; stage kt+1 -> RB^1 (8 gloads);
// read 16 frags from RB; 32 MFMA (compiler emits counted lgkmcnt).
// T2 both-sides swizzle: 16B slot ^= (row&7) at the GLOBAL source and on
// ds_read (rule #21) -> 0 bank conflicts. NT-inner block order: A-panel L2
// reuse (round 6). XCD-bijective swizzle (grids %8==0).
template<int OUT_B16, int B_PER_B, int LDA, int K_>
__global__ __launch_bounds__(256, 2)
void gemm128(const unsigned short* __restrict__ A, int a_off,
             const unsigned short* __restrict__ Bt,
             const float* __restrict__ bias,
             void* __restrict__ Outp, int ldo, int Ntiles)
{
  __shared__ unsigned short As[2][128][64];   // 32 KiB
  __shared__ unsigned short Bs[2][128][64];   // 32 KiB
  const int t = threadIdx.x;
  const int lane = t & 63, w = t >> 6;
  const int wr = w >> 1, wc = w & 1;          // 2M x 2N wave grid
  // XCD-aware bijective swizzle (gridDim.x % 8 == 0 for all launches here)
  const int nwg = gridDim.x, cpx = nwg >> 3;
  const int bid = (int)blockIdx.x;
  const int swz = (bid & 7) * cpx + (bid >> 3);
  const int mt = swz / Ntiles, nt = swz % Ntiles;   // nt-inner: A-panel reuse
  const long m0 = (long)mt * 128;
  const int  n0 = nt * 128;
  const unsigned short* B0p = Bt + (B_PER_B ? (long)(m0 / N_) * C_ * C_ : 0);
  // staging lane geometry: lane covers (row rowin of an 8-row group, slot L&7)
  const int rowin = lane >> 3;
  const int swzc  = ((lane & 7) ^ rowin) * 8;         // pre-swizzled global col
  const unsigned short* Ag = A + a_off + (m0 + rowin) * (long)LDA + swzc;
  const unsigned short* Bg = B0p + (long)(n0 + rowin) * (long)K_ + swzc;
  const int KT = K_ / 64;                              // 12 (even)

#define STG_A(wb, k0g) do{ _Pragma("unroll")                               \
  for (int j_ = 0; j_ < 4; ++j_){                                          \
    const int rg_ = (j_*4 + w)*8;                                          \
    GLOAD_LDS16(Ag + (long)rg_*LDA + (k0g), &As[wb][rg_][0]); } }while(0)
#define STG_B(wb, k0g) do{ _Pragma("unroll")                               \
  for (int j_ = 0; j_ < 4; ++j_){                                          \
    const int rg_ = (j_*4 + w)*8;                                          \
    GLOAD_LDS16(Bg + (long)rg_*K_ + (k0g), &Bs[wb][rg_][0]); } }while(0)

  const int l15 = lane & 15, l4 = lane >> 4, x7 = l15 & 7;
  const int ca = (l4 ^ x7) * 8;        // kh=0 swizzled elem col
  const int cb = ((4 + l4) ^ x7) * 8;  // kh=1 swizzled elem col

  f32x4 acc[4][4] = {};
  short8 af[2][4], bf[2][4];

#define RD_AB(RB) do{ _Pragma("unroll")                                    \
  for (int i_ = 0; i_ < 4; ++i_){                                          \
    const int ra_ = wr*64 + i_*16 + l15;                                   \
    af[0][i_] = *(const short8*)&As[RB][ra_][ca];                          \
    af[1][i_] = *(const short8*)&As[RB][ra_][cb];                          \
  }                                                                        \
  _Pragma("unroll")                                                        \
  for (int i_ = 0; i_ < 4; ++i_){                                          \
    const int rb_ = wc*64 + i_*16 + l15;                                   \
    bf[0][i_] = *(const short8*)&Bs[RB][rb_][ca];                          \
    bf[1][i_] = *(const short8*)&Bs[RB][rb_][cb];                          \
  } }while(0)

#define MFMA_ALL() do{                                                     \
    __builtin_amdgcn_s_setprio(1);                                         \
    _Pragma("unroll")                                                      \
    for (int kh_ = 0; kh_ < 2; ++kh_)                                      \
      _Pragma("unroll")                                                    \
      for (int m_ = 0; m_ < 4; ++m_)                                       \
        _Pragma("unroll")                                                  \
        for (int n_ = 0; n_ < 4; ++n_)                                     \
          acc[m_][n_] = __builtin_amdgcn_mfma_f32_16x16x32_bf16(           \
              af[kh_][m_], bf[kh_][n_], acc[m_][n_], 0, 0, 0);             \
    __builtin_amdgcn_s_setprio(0);                                         \
  }while(0)

#define BARRIER()  asm volatile("s_barrier" ::: "memory")
#define WAITVM0()  asm volatile("s_waitcnt vmcnt(0)" ::: "memory")
#define SB0()      __builtin_amdgcn_sched_barrier(0)

// One K-tile, buffer index RB is a literal. Stages tile kt+1 into RB^1.
// Safety: all RB^1 reads of tile kt-1 completed before their MFMAs issued,
// which precede this barrier -> post-barrier stages into RB^1 cannot race.
#define TILE(RB, kt_, ST_) do{                                             \
    const int k1_ = ((kt_) + 1) * 64;                                      \
    WAITVM0();                        /* tile kt's stage loads landed */   \
    BARRIER();                                                             \
    if (ST_){ STG_B((RB)^1, k1_); STG_A((RB)^1, k1_); }                    \
    SB0();                            /* gloads issue before ds_reads */   \
    RD_AB(RB);                                                             \
    SB0();                                                                 \
    MFMA_ALL();                                                            \
  }while(0)

  // prologue: stage tile 0 into buf 0
  STG_B(0, 0); STG_A(0, 0);

  #pragma unroll 1
  for (int it = 0; it < KT/2; ++it){
    const int kt0 = it*2;
    TILE(0, kt0, true);                      // kt0 <= KT-2: always stages
    TILE(1, kt0 + 1, (kt0 + 1) < (KT - 1));  // last tile stages nothing
  }

#undef TILE
#undef SB0
#undef WAITVM0
#undef BARRIER
#undef MFMA_ALL
#undef RD_AB
#undef STG_B
#undef STG_A

  // epilogue: C write (C/D layout: col=lane&15, row=(lane>>4)*4+j)
  const int rl = l4 * 4, cl = l15;
  #pragma unroll
  for (int mi = 0; mi < 4; ++mi){
    const long gr = m0 + wr*64 + mi*16 + rl;
    #pragma unroll
    for (int ni = 0; ni < 4; ++ni){
      const int gc = n0 + wc*64 + ni*16 + cl;
      const float bv = bias[gc];
      #pragma unroll
      for (int j = 0; j < 4; ++j){
        float v = acc[mi][ni][j] + bv;
        if (OUT_B16) ((unsigned short*)Outp)[(gr + j)*(long)ldo + gc] = f2b(v);
        else         ((float*)Outp)[(gr + j)*(long)ldo + gc] = v;
      }
    }
  }
}

// ---------------- K2: per (b,h,split) 128x128 Gram of stacked [q|k] ------
__global__ __launch_bounds__(256)
void gram_qk(const unsigned short* __restrict__ qkv, float* __restrict__ part)
{
  __shared__ unsigned short Xs[2][128][72];   // padded: conflict-light ds_read
  const int sp = blockIdx.x;               // 0..SPLITS-1
  const int bh = blockIdx.y;               // 0..47
  const int b = bh / H_, h = bh % H_;
  const int t = threadIdx.x, lane = t & 63, w = t >> 6, wr = w >> 1, wc = w & 1;
  f32x4 acc[4][4] = {};
  const long rowbase = (long)b * N_ + (long)sp * NCHUNK;
  const int c8  = t & 15;                  // channel-octet this thread stages
  const int col = (c8 < 8) ? (h*HD_ + c8*8) : (C_ + h*HD_ + (c8 - 8)*8);
  const int nl0 = t >> 4;                  // base n-row (i adds 16)
  uint4 r[4];

  #pragma unroll
  for (int i = 0; i < 4; ++i)
    r[i] = *(const uint4*)(qkv + (rowbase + i*16 + nl0)*N1_ + col);

  int cur = 0;
  for (int st = 0; st < NCHUNK/64; ++st){
    #pragma unroll
    for (int i = 0; i < 4; ++i){
      const unsigned short* pv = (const unsigned short*)&r[i];
      #pragma unroll
      for (int j = 0; j < 8; ++j) Xs[cur][c8*8 + j][i*16 + nl0] = pv[j];
    }
    if (st + 1 < NCHUNK/64){
      #pragma unroll
      for (int i = 0; i < 4; ++i)
        r[i] = *(const uint4*)(qkv + (rowbase + (st+1)*64 + i*16 + nl0)*N1_ + col);
    }
    asm volatile("s_waitcnt lgkmcnt(0)" ::: "memory");  // ds_writes visible
    __builtin_amdgcn_s_barrier();                        // vmcnt stays in flight
    asm volatile("" ::: "memory");
    #pragma unroll
    for (int kk = 0; kk < 2; ++kk){
      const int koff = kk*32 + (lane >> 4) * 8;
      short8 a[4], bb[4];
      #pragma unroll
      for (int m = 0; m < 4; ++m)
        a[m] = *(const short8*)&Xs[cur][wr*64 + m*16 + (lane & 15)][koff];
      #pragma unroll
      for (int n = 0; n < 4; ++n)
        bb[n] = *(const short8*)&Xs[cur][wc*64 + n*16 + (lane & 15)][koff];
      #pragma unroll
      for (int m = 0; m < 4; ++m)
        #pragma unroll
        for (int n = 0; n < 4; ++n)
          acc[m][n] = __builtin_amdgcn_mfma_f32_16x16x32_bf16(a[m], bb[n], acc[m][n], 0, 0, 0);
    }
    cur ^= 1;
  }
  float* P = part + ((long)bh*SPLITS + sp) * 128 * 128;
  const int rl = (lane >> 4) * 4, cl = lane & 15;
  #pragma unroll
  for (int m = 0; m < 4; ++m)
    #pragma unroll
    for (int n = 0; n < 4; ++n)
      #pragma unroll
      for (int j = 0; j < 4; ++j)
        P[(wr*64 + m*16 + rl + j)*128 + wc*64 + n*16 + cl] = acc[m][n][j];
}

// ---------------- K3: reduce partials, norms, softmax -> attn ------------
// Vectorized: f32x4 loads over e, softmax fully in-register (no sl LDS).
__global__ __launch_bounds__(64)
void softmax_attn(const float* __restrict__ part, const float* __restrict__ temperature,
                  float* __restrict__ attn)
{
  const int bh = blockIdx.x, h = bh % H_;
  const int d = threadIdx.x;
  __shared__ float rnk[64];
  const float* P = part + (long)bh * SPLITS * 16384;
  float nq2 = 0.f, nk2 = 0.f;
  for (int s = 0; s < SPLITS; ++s){
    nq2 += P[s*16384 + d*128 + d];
    nk2 += P[s*16384 + (64 + d)*128 + 64 + d];
  }
  const float rq = 1.0f / fmaxf(sqrtf(nq2), 1e-12f);
  rnk[d] = 1.0f / fmaxf(sqrtf(nk2), 1e-12f);
  __syncthreads();
  f32x4 se[16] = {};
  for (int sp = 0; sp < SPLITS; ++sp){
    const float* row = P + sp*16384 + d*128 + 64;
    #pragma unroll
    for (int i = 0; i < 16; ++i) se[i] += *(const f32x4*)(row + i*4);
  }
  const float th = temperature[h];
  float mx = -1e30f;
  #pragma unroll
  for (int i = 0; i < 16; ++i)
    #pragma unroll
    for (int j = 0; j < 4; ++j){
      float v = th * se[i][j] * rq * rnk[i*4 + j];
      se[i][j] = v;
      mx = fmaxf(mx, v);
    }
  float sum = 0.f;
  #pragma unroll
  for (int i = 0; i < 16; ++i)
    #pragma unroll
    for (int j = 0; j < 4; ++j){
      float ex = expf(se[i][j] - mx);
      se[i][j] = ex;
      sum += ex;
    }
  const float rs = 1.0f / sum;
  float* dst = attn + (long)bh*4096 + d*64;
  #pragma unroll
  for (int i = 0; i < 16; ++i){
    f32x4 o = se[i] * rs;
    *(f32x4*)(dst + i*4) = o;
  }
}

// ---------------- K4: WcombT[b][j][h*64+e] = sum_d attn[d][e]*Wproj[h*64+d][j]
__global__ __launch_bounds__(256)
void wcomb(const float* __restrict__ attn, const float* __restrict__ Wproj,
           unsigned short* __restrict__ WcT)
{
  const int bh = blockIdx.x;            // 0..47
  const int jt = blockIdx.y;            // 0..5
  const int b = bh / H_, h = bh % H_;
  __shared__ float sa[64][64];
  const int t = threadIdx.x;
  #pragma unroll
  for (int i = 0; i < 16; ++i){
    int idx = i*256 + t;
    sa[idx >> 6][idx & 63] = attn[(long)bh*4096 + idx];
  }
  __syncthreads();
  const int j  = jt*128 + (t & 127);
  const int e0 = (t >> 7) * 32;
  float acc[32] = {};
  for (int d = 0; d < 64; ++d){
    float wp = Wproj[(long)(h*HD_ + d)*C_ + j];
    #pragma unroll
    for (int i = 0; i < 32; ++i) acc[i] += sa[d][e0 + i] * wp;
  }
  #pragma unroll
  for (int i = 0; i < 32; ++i)
    WcT[((long)b*C_ + j)*C_ + h*HD_ + e0 + i] = f2b(acc[i]);
}

// ---------------- launch --------------------------------------------------
extern "C" void kernel_launch(void* const* d_in, const int* in_sizes, int n_in,
                              void* d_out, int out_size, void* d_ws, size_t ws_size,
                              hipStream_t stream)
{
  const float* x      = (const float*)d_in[0];
  const float* Wqkv   = (const float*)d_in[1];
  const float* bqkv   = (const float*)d_in[2];
  const float* temper = (const float*)d_in[3];
  const float* Wproj  = (const float*)d_in[4];
  const float* bproj  = (const float*)d_in[5];
  float* out = (float*)d_out;

  char* wp = (char*)d_ws;
  unsigned short* qkvB  = (unsigned short*)wp; wp += (size_t)MTOT * N1_ * 2;      // 151.0 MB
  unsigned short* WqkvT = (unsigned short*)wp; wp += (size_t)N1_ * C_ * 2;        // 3.5 MB
  unsigned short* WcT   = (unsigned short*)wp; wp += (size_t)B_ * C_ * C_ * 2;    // 4.7 MB
  float* part           = (float*)wp;          wp += (size_t)48 * SPLITS * 128 * 128 * 4; // 25.2 MB
  float* attn           = (float*)wp;          wp += (size_t)48 * 64 * 64 * 4;    // 0.79 MB
  // xB (48 MB) lives in d_out (96 MB fp32): consumed by K1, then K5 fully
  // overwrites d_out. Deterministic: same sequence every call.
  unsigned short* xB = (unsigned short*)d_out;

  // K0: WqkvT
  transpose_w<<<(N1_/32) * (C_/32), 256, 0, stream>>>(Wqkv, WqkvT, C_, N1_);
  // Kc: xB = bf16(x)
  cvt_bf16<<<2048, 256, 0, stream>>>(x, xB, (long)MTOT * C_ / 8);
  // K1: qkvB = bf16(xB @ Wqkv + bqkv); grid 256 x 18 = 4608 (%8==0), nt-inner
  gemm128<1,0,C_,C_><<<(MTOT/128) * (N1_/128), 256, 0, stream>>>(
      xB, 0, WqkvT, bqkv, (void*)qkvB, N1_, N1_/128);
  // K2: Gram partials
  gram_qk<<<dim3(SPLITS, 48), 256, 0, stream>>>(qkvB, part);
  // K3: softmax
  softmax_attn<<<48, 64, 0, stream>>>(part, temper, attn);
  // K4: combined weights
  wcomb<<<dim3(48, 6), 256, 0, stream>>>(attn, Wproj, WcT);
  // K5: out = V @ Wcomb[b] + bproj; grid 256 x 6 = 1536 (%8==0), nt-inner
  gemm128<0,1,N1_,C_><<<(MTOT/128) * (C_/128), 256, 0, stream>>>(
      qkvB, 2*C_, WcT, bproj, (void*)out, C_, C_/128);
}